// Round 6
// baseline (1015.108 us; speedup 1.0000x reference)
//
#include <hip/hip_runtime.h>
#include <hip/hip_bf16.h>

// Problem constants
#define NB 4
#define NT 256
#define NU 128
#define DENC 512
#define DPRED 640
#define NH 640
#define NV 1025
#define NVP 1088      // V padded to 68 tiles of 16 -> 17 tiles per n-group (4 groups)
#define NTILES 68
#define JT 17         // tiles per n-group
#define KSTEPS 20     // 640 / 32
#define WSLAB (NVP * 32)   // 34816 bf16 elems per k-slab (69632 B)

typedef __attribute__((ext_vector_type(8))) short short8;
typedef __attribute__((ext_vector_type(4))) float f32x4;

__device__ __forceinline__ unsigned short bfu(float a) {
    union { __hip_bfloat16 h; unsigned short u; } cv;
    cv.h = __float2bfloat16(a);
    return cv.u;
}

__device__ __forceinline__ unsigned pk2(float a, float b) {
    union { __hip_bfloat162 h; unsigned u; } cv;
    cv.h = __float22bfloat162_rn(float2{a, b});
    return cv.u;
}

__device__ __forceinline__ short8 pack_relu(f32x4 x, f32x4 y) {
    union { short8 s; unsigned u[4]; } r;
    r.u[0] = pk2(fmaxf(x[0], 0.f), fmaxf(x[1], 0.f));
    r.u[1] = pk2(fmaxf(x[2], 0.f), fmaxf(x[3], 0.f));
    r.u[2] = pk2(fmaxf(y[0], 0.f), fmaxf(y[1], 0.f));
    r.u[3] = pk2(fmaxf(y[2], 0.f), fmaxf(y[3], 0.f));
    return r.s;
}

// async global -> LDS, 16 B per lane; LDS dest = wave-uniform base + lane*16
__device__ __forceinline__ void gload_lds16(const void* g, void* l) {
    __builtin_amdgcn_global_load_lds(
        (const __attribute__((address_space(1))) unsigned int*)g,
        (__attribute__((address_space(3))) unsigned int*)l, 16, 0, 0);
}

// prep: W_out fp32 [1025][640] -> WbT bf16 [21][1088][32] (k-slab-major; slab 20
// is a zero dummy so the joint loop can prefetch branch-free on its last iter).
// LDS bank-swizzle pre-baked: (r, slot s) holds source slot s ^ f(r),
// f(r) = ((r>>2)^r)&3. Consumer reads slot kgrp^f(row) -> original data.
// bias -> [1088], pads = -1e30. Grid: dim3(136, 21).
__global__ __launch_bounds__(256) void prep_kernel(const float* __restrict__ Wo,
                                                   const float* __restrict__ bo,
                                                   unsigned short* __restrict__ WbT,
                                                   float* __restrict__ biasp) {
    int idx = blockIdx.x * 256 + threadIdx.x;     // 0 .. 34815 within slab
    int ks = blockIdx.y;                          // 0 .. 20
    int r = idx >> 5;         // row 0..1087
    int kk = idx & 31;        // 0..31 within slab row
    int s = kk >> 3, e = kk & 7;
    int f = ((r >> 2) ^ r) & 3;
    int scol = ks * 32 + (((s ^ f) & 3) << 3) + e;
    unsigned short val = 0;
    if (ks < KSTEPS && r < NV) val = bfu(Wo[r * NH + scol]);
    WbT[(size_t)ks * WSLAB + idx] = val;
    if (ks == 0 && idx < NVP) biasp[idx] = (idx < NV) ? bo[idx] : -1e30f;
}

// Projection GEMM: out[b*L + l][n] = sum_k X[b][k][l] * W[n][k] + bias[n]
__global__ __launch_bounds__(256) void proj_kernel(const float* __restrict__ X,
                                                   const float* __restrict__ W,
                                                   const float* __restrict__ bias,
                                                   float* __restrict__ out,
                                                   int L, int K) {
    __shared__ unsigned short As[32][40];
    __shared__ unsigned short Bs[64][40];
    int tid = threadIdx.x;
    int wave = tid >> 6, lane = tid & 63;
    int col16 = lane & 15, kgrp = lane >> 4;
    int m0 = blockIdx.x * 32;
    int n0 = blockIdx.y * 64;
    int b = m0 / L, l0 = m0 % L;
    const float* Xb = X + (size_t)b * K * L;

    float bv = bias[n0 + wave * 16 + col16];
    f32x4 c0 = {bv, bv, bv, bv};
    f32x4 c1 = c0;

    int ac = tid >> 3;
    int ar = (tid & 7) * 4;
    int bn = tid >> 2;
    int bc = (tid & 3) * 8;

    for (int k0 = 0; k0 < K; k0 += 32) {
        f32x4 av  = *(const f32x4*)(Xb + (size_t)(k0 + ac) * L + l0 + ar);
        f32x4 bw0 = *(const f32x4*)(W + (size_t)(n0 + bn) * K + k0 + bc);
        f32x4 bw1 = *(const f32x4*)(W + (size_t)(n0 + bn) * K + k0 + bc + 4);
        __syncthreads();
        As[ar + 0][ac] = bfu(av[0]);
        As[ar + 1][ac] = bfu(av[1]);
        As[ar + 2][ac] = bfu(av[2]);
        As[ar + 3][ac] = bfu(av[3]);
        unsigned* bsrow = (unsigned*)&Bs[bn][bc];
        bsrow[0] = pk2(bw0[0], bw0[1]);
        bsrow[1] = pk2(bw0[2], bw0[3]);
        bsrow[2] = pk2(bw1[0], bw1[1]);
        bsrow[3] = pk2(bw1[2], bw1[3]);
        __syncthreads();
        short8 a0  = *(const short8*)&As[col16][kgrp * 8];
        short8 a1  = *(const short8*)&As[16 + col16][kgrp * 8];
        short8 bfr = *(const short8*)&Bs[wave * 16 + col16][kgrp * 8];
        c0 = __builtin_amdgcn_mfma_f32_16x16x32_bf16(a0, bfr, c0, 0, 0, 0);
        c1 = __builtin_amdgcn_mfma_f32_16x16x32_bf16(a1, bfr, c1, 0, 0, 0);
    }
    int n = n0 + wave * 16 + col16;
    #pragma unroll
    for (int i = 0; i < 4; ++i) {
        int r0 = kgrp * 4 + i;
        out[(size_t)(m0 + r0) * NH + n]      = c0[i];
        out[(size_t)(m0 + 16 + r0) * NH + n] = c1[i];
    }
}

// Joint kernel v7: M=64, 512 thr, 8 waves = 2(wm) x 4(wn). One shared W slab
// per block (halves per-CU L2 W-traffic vs 2x256 blocks): both wm waves of a
// wn-group read the same 17 LDS tiles; staging split wm0:9 / wm1:8. Full
// double-buffered slab (2x68KB). Sync: raw s_barrier + counted vmcnt(12)
// (never 0) -- loads stay in flight across barriers. 2 barriers/k-step.
__global__ __launch_bounds__(512, 2) void joint_kernel(const float* __restrict__ f,
                                                       const float* __restrict__ g,
                                                       const unsigned short* __restrict__ WbT,
                                                       const float* __restrict__ biasp,
                                                       float* __restrict__ out) {
    __shared__ unsigned short Ws[2][WSLAB];   // 2 x 69632 B
    __shared__ float fs[NH];
    __shared__ float redm[8][32];
    __shared__ float reds[8][32];
    int tid = threadIdx.x;
    int wave = tid >> 6, lane = tid & 63;
    int wm = wave >> 2, wn = wave & 3;
    int col16 = lane & 15, kgrp = lane >> 4;
    int bt = blockIdx.x >> 1;          // b*NT + t
    int u0 = (blockIdx.x & 1) * 64;
    int b = bt >> 8;                   // NT = 256

    for (int i = tid; i < NH; i += 512) fs[i] = f[(size_t)bt * NH + i];

    int tstart = wn * JT;              // 0,17,34,51
    // staging split: wm0 stages tiles [tstart, tstart+9), wm1 [tstart+9, tstart+17)
    int sbase = tstart + (wm ? 9 : 0);
    int scnt  = wm ? 8 : 9;

    const float* gp0 = g + (size_t)(b * NU + u0 + wm * 32 + col16) * NH + kgrp * 8;
    const float* gp1 = gp0 + 16 * NH;

    f32x4 c[JT][2];
    #pragma unroll
    for (int j = 0; j < JT; ++j) {
        float bv = biasp[(tstart + j) * 16 + col16];
        f32x4 cv = {bv, bv, bv, bv};
        c[j][0] = cv; c[j][1] = cv;
    }

    // consumer-side swizzled slot (lane-invariant)
    int slx = ((kgrp ^ ((col16 >> 2) ^ col16)) & 3) * 8;
    int rdbase = col16 * 32 + slx;

    __syncthreads();   // fs visible (full drain, once, outside hot loop)

    // ---- prologue: g(0) loads + stage slab 0 into buf 0 ----
    f32x4 ga0 = *(const f32x4*)(gp0);
    f32x4 ga1 = *(const f32x4*)(gp0 + 4);
    f32x4 gb0 = *(const f32x4*)(gp1);
    f32x4 gb1 = *(const f32x4*)(gp1 + 4);
    for (int jj = 0; jj < scnt; ++jj)
        gload_lds16(WbT + (size_t)(sbase + jj) * 512 + lane * 8,
                    &Ws[0][(sbase + jj) * 512]);

    int cur = 0;
    for (int ks = 0; ks < KSTEPS; ++ks) {
        int kb = ks * 32 + kgrp * 8;
        f32x4 fa0 = *(const f32x4*)(fs + kb);
        f32x4 fa1 = *(const f32x4*)(fs + kb + 4);
        // compiler inserts counted vmcnt for g(ks) (oldest in queue)
        short8 a0 = pack_relu(fa0 + ga0, fa1 + ga1);
        short8 a1 = pack_relu(fa0 + gb0, fa1 + gb1);
        // issue g(ks+1) (ks=19 reads in-bounds garbage past row end)
        ga0 = *(const f32x4*)(gp0 + (ks + 1) * 32);
        ga1 = *(const f32x4*)(gp0 + (ks + 1) * 32 + 4);
        gb0 = *(const f32x4*)(gp1 + (ks + 1) * 32);
        gb1 = *(const f32x4*)(gp1 + (ks + 1) * 32 + 4);
        // issue stage(ks+1) into buf^1 (its readers finished at ks-1's barrier #2;
        // slab 20 is the zero dummy)
        {
            const unsigned short* wnp = WbT + (size_t)(ks + 1) * WSLAB;
            #pragma unroll
            for (int jj = 0; jj < 9; ++jj)
                if (jj < scnt)
                    gload_lds16(wnp + (size_t)(sbase + jj) * 512 + lane * 8,
                                &Ws[cur ^ 1][(sbase + jj) * 512]);
        }
        // wait own stage(ks) landed: queue [stage_ks(scnt), g_next(4), stage_next(scnt)]
        // vmcnt(12): wm0 (scnt=9) drains stage_ks + 1 g (g is long-landed, L2-resident);
        // wm1 (scnt=8) drains exactly stage_ks. Uniform count, wave-safe.
        asm volatile("s_waitcnt vmcnt(12)" ::: "memory");
        __builtin_amdgcn_sched_barrier(0);
        __builtin_amdgcn_s_barrier();      // #1: ALL waves' stage(ks) landed -> buf[cur] ready
        __builtin_amdgcn_s_setprio(1);
        #pragma unroll
        for (int jj = 0; jj < JT; ++jj) {
            short8 bj = *(const short8*)(&Ws[cur][(tstart + jj) * 512 + rdbase]);
            c[jj][0] = __builtin_amdgcn_mfma_f32_16x16x32_bf16(a0, bj, c[jj][0], 0, 0, 0);
            c[jj][1] = __builtin_amdgcn_mfma_f32_16x16x32_bf16(a1, bj, c[jj][1], 0, 0, 0);
        }
        __builtin_amdgcn_s_setprio(0);
        asm volatile("s_waitcnt lgkmcnt(0)" ::: "memory");   // own reads of buf[cur] retired
        __builtin_amdgcn_sched_barrier(0);
        __builtin_amdgcn_s_barrier();      // #2: all reads done -> buf[cur] overwritable next iter
        cur ^= 1;
    }

    __syncthreads();   // drains dummy prefetches; sync for reductions

    // ---- fused log-softmax epilogue ----
    // C layout: col = tile*16 + (lane&15); row = wm*32 + m*16 + (lane>>4)*4 + reg
    float mx[2][4], sl[2][4];
    #pragma unroll
    for (int m = 0; m < 2; ++m) {
        #pragma unroll
        for (int i = 0; i < 4; ++i) {
            float v = -3e38f;
            #pragma unroll
            for (int j = 0; j < JT; ++j) v = fmaxf(v, c[j][m][i]);
            #pragma unroll
            for (int d = 1; d < 16; d <<= 1)
                v = fmaxf(v, __shfl_xor(v, d, 64));
            mx[m][i] = v;
        }
    }
    if (col16 == 0) {
        #pragma unroll
        for (int m = 0; m < 2; ++m)
            #pragma unroll
            for (int i = 0; i < 4; ++i)
                redm[wave][m * 16 + kgrp * 4 + i] = mx[m][i];
    }
    __syncthreads();
    #pragma unroll
    for (int m = 0; m < 2; ++m)
        #pragma unroll
        for (int i = 0; i < 4; ++i) {
            int r = m * 16 + kgrp * 4 + i;
            int wb = wm * 4;
            mx[m][i] = fmaxf(fmaxf(redm[wb][r], redm[wb + 1][r]),
                             fmaxf(redm[wb + 2][r], redm[wb + 3][r]));
        }
    #pragma unroll
    for (int m = 0; m < 2; ++m) {
        #pragma unroll
        for (int i = 0; i < 4; ++i) {
            float ssum = 0.f;
            #pragma unroll
            for (int j = 0; j < JT; ++j) ssum += __expf(c[j][m][i] - mx[m][i]);
            #pragma unroll
            for (int d = 1; d < 16; d <<= 1)
                ssum += __shfl_xor(ssum, d, 64);
            sl[m][i] = ssum;
        }
    }
    if (col16 == 0) {
        #pragma unroll
        for (int m = 0; m < 2; ++m)
            #pragma unroll
            for (int i = 0; i < 4; ++i)
                reds[wave][m * 16 + kgrp * 4 + i] = sl[m][i];
    }
    __syncthreads();
    #pragma unroll
    for (int m = 0; m < 2; ++m)
        #pragma unroll
        for (int i = 0; i < 4; ++i) {
            int r = m * 16 + kgrp * 4 + i;
            int wb = wm * 4;
            float S = (reds[wb][r] + reds[wb + 1][r]) + (reds[wb + 2][r] + reds[wb + 3][r]);
            sl[m][i] = mx[m][i] + __logf(S);   // m + log(sum exp(x-m))
        }

    size_t orow0 = (size_t)bt * NU + u0 + wm * 32;
    #pragma unroll
    for (int m = 0; m < 2; ++m) {
        #pragma unroll
        for (int j = 0; j < JT; ++j) {
            int col = (tstart + j) * 16 + col16;
            if (col < NV) {
                #pragma unroll
                for (int i = 0; i < 4; ++i) {
                    size_t row = orow0 + m * 16 + kgrp * 4 + i;
                    out[row * (size_t)NV + col] = c[j][m][i] - sl[m][i];
                }
            }
        }
    }
}

extern "C" void kernel_launch(void* const* d_in, const int* in_sizes, int n_in,
                              void* d_out, int out_size, void* d_ws, size_t ws_size,
                              hipStream_t stream) {
    const float* enc    = (const float*)d_in[0];  // [4][512][256]
    const float* dec    = (const float*)d_in[1];  // [4][640][128]
    const float* W_enc  = (const float*)d_in[2];  // [640][512]
    const float* b_enc  = (const float*)d_in[3];  // [640]
    const float* W_pred = (const float*)d_in[4];  // [640][640]
    const float* b_pred = (const float*)d_in[5];  // [640]
    const float* W_out  = (const float*)d_in[6];  // [1025][640]
    const float* b_out  = (const float*)d_in[7];  // [1025]
    float* out = (float*)d_out;

    char* ws = (char*)d_ws;
    unsigned short* WbT = (unsigned short*)ws;         // 1,462,272 B (bf16 [21][1088][32])
    float* biasp = (float*)(ws + 1462272);             // 4,352 B
    float* fbuf  = (float*)(ws + 1466624);             // 2,621,440 B ([1024][640] fp32)
    float* gbuf  = (float*)(ws + 4088064);             // 1,310,720 B ([512][640] fp32)

    prep_kernel<<<dim3(WSLAB / 256, KSTEPS + 1), 256, 0, stream>>>(W_out, b_out, WbT, biasp);
    proj_kernel<<<dim3((NB * NT) / 32, NH / 64), 256, 0, stream>>>(enc, W_enc, b_enc, fbuf, NT, DENC);
    proj_kernel<<<dim3((NB * NU) / 32, NH / 64), 256, 0, stream>>>(dec, W_pred, b_pred, gbuf, NU, DPRED);
    joint_kernel<<<NB * NT * (NU / 64), 512, 0, stream>>>(fbuf, gbuf, WbT, biasp, out);
}